// Round 16
// baseline (526.802 us; speedup 1.0000x reference)
//
#include <hip/hip_runtime.h>
#include <hip/hip_bf16.h>
#include <math.h>

#define NEG_SLOPE 0.2f

typedef __attribute__((ext_vector_type(8))) short bf16x8;
typedef __attribute__((ext_vector_type(4))) float f32x4;

__device__ __forceinline__ float sigmoidf(float x){ return 1.f/(1.f+expf(-x)); }
__device__ __forceinline__ float bf2f(unsigned us){ return __uint_as_float(us << 16); }
__device__ __forceinline__ unsigned short bf16of(float v){
  __hip_bfloat16 h = __float2bfloat16(v);
  return __builtin_bit_cast(unsigned short, h);
}

// ============== init + CSR prep + weight packing (one launch) ===============
__global__ void init_kernel(int* counts, int* gstart, int* gend, float* sdbuf,
                            int* pad1, int* pad2, int npadints,
                            const float* __restrict__ W1, unsigned short* __restrict__ WT1,
                            const float* __restrict__ W2, unsigned short* __restrict__ WT2,
                            const float* __restrict__ W3, unsigned short* __restrict__ WT3,
                            int n, int b){
  int i = blockIdx.x*blockDim.x + threadIdx.x;
  if (i < n) counts[i] = 0;
  if (i < b){ gstart[i] = 0; gend[i] = 0; }
  if (i < 18*n) sdbuf[i] = 0.f;
  if (i < npadints){ pad1[i] = 0; pad2[i] = 0; }
  if (i < 128*256){                 // W1 [128,256] -> WT1 [256][128]
    int k = i>>8, c = i&255;
    WT1[(size_t)c*128 + k] = bf16of(W1[i]);
  }
  if (i < 256*256){                 // W2 [256,256] -> WT2 [256][256]
    int k = i>>8, c = i&255;
    WT2[(size_t)c*256 + k] = bf16of(W2[i]);
  }
  if (i < 256*128){                 // W3 [256,128] -> WT3 [128][256]
    int k = i>>7, c = i&127;
    WT3[(size_t)c*256 + k] = bf16of(W3[i]);
  }
}

__global__ void build_kernel(const int* __restrict__ ei, const int* __restrict__ batch,
                             int* counts, int* gstart, int* gend, int E, int n){
  int i = blockIdx.x*blockDim.x + threadIdx.x;
  if (i < E) atomicAdd(&counts[ei[E+i]], 1);
  if (i < n){
    int b = batch[i];
    if (i == 0 || batch[i-1] != b) gstart[b] = i;
    if (i == n-1 || batch[i+1] != b) gend[b] = i+1;
  }
}

__global__ void scan_kernel(const int* __restrict__ counts, int* offs, int* cursor, int n){
  const int T = 1024;
  int tid = threadIdx.x;
  int chunk = (n + T - 1)/T;
  int base = tid*chunk;
  int local = 0;
  for (int i=0;i<chunk;i++){ int idx=base+i; if (idx<n) local += counts[idx]; }
  __shared__ int ss[T];
  ss[tid]=local; __syncthreads();
  for (int off=1; off<T; off<<=1){
    int v = (tid>=off)? ss[tid-off] : 0;
    __syncthreads();
    ss[tid]+=v;
    __syncthreads();
  }
  int run = ss[tid]-local;
  for (int i=0;i<chunk;i++){
    int idx=base+i;
    if (idx<n){ offs[idx]=run; cursor[idx]=run; run += counts[idx]; }
  }
  if (tid==T-1) offs[n]=run;
}

__global__ void fill_kernel(const int* __restrict__ ei, int* cursor, int* csr, int E){
  int i = blockIdx.x*blockDim.x + threadIdx.x;
  if (i<E){
    int dst = ei[E+i];
    int pos = atomicAdd(&cursor[dst],1);
    csr[pos] = ei[i];
  }
}

// ========================= plain-bf16 MFMA GEMM =============================
template<bool AF32, int H>
__global__ __launch_bounds__(256) void gemm_bf16(
    const void* __restrict__ Aptr, const short* __restrict__ BT,
    unsigned short* __restrict__ Cb16,
    const float* __restrict__ asrc, const float* __restrict__ adst,
    float* __restrict__ sv, float* __restrict__ dv,
    int M, int Ktot, int N){
  __shared__ short As[64][72];
  __shared__ short Bs[128][72];
  int tid = threadIdx.x;
  int wave = tid>>6, lane = tid&63;
  int quad = lane>>4, l16 = lane&15;
  int bm = blockIdx.y*64, bn = blockIdx.x*128;
  f32x4 acc[8];
  #pragma unroll
  for (int i=0;i<8;i++) acc[i] = (f32x4){0.f,0.f,0.f,0.f};
  int rr = tid>>3;          // 0..31
  int seg = (tid&7)*8;      // shorts (= bf16 elements = k index)
  int4 ra[2], rb[4];
  auto loadAB = [&](int k0){
    if (AF32){
      const float* A = (const float*)Aptr;
      #pragma unroll
      for (int p=0;p<2;p++){
        int row = bm + p*32 + rr;
        float4 v0 = make_float4(0.f,0.f,0.f,0.f), v1 = v0;
        if (row < M){
          const float* ap = A + (size_t)row*Ktot + k0 + seg;
          v0 = *(const float4*)(ap);
          v1 = *(const float4*)(ap+4);
        }
        unsigned u0 = (unsigned)bf16of(v0.x) | ((unsigned)bf16of(v0.y)<<16);
        unsigned u1 = (unsigned)bf16of(v0.z) | ((unsigned)bf16of(v0.w)<<16);
        unsigned u2 = (unsigned)bf16of(v1.x) | ((unsigned)bf16of(v1.y)<<16);
        unsigned u3 = (unsigned)bf16of(v1.z) | ((unsigned)bf16of(v1.w)<<16);
        ra[p] = make_int4((int)u0,(int)u1,(int)u2,(int)u3);
      }
    } else {
      const short* A = (const short*)Aptr;
      #pragma unroll
      for (int p=0;p<2;p++)
        ra[p] = *(const int4*)(A + (size_t)(bm + p*32 + rr)*Ktot + k0 + seg);
    }
    #pragma unroll
    for (int p=0;p<4;p++)
      rb[p] = *(const int4*)(BT + (size_t)(bn + p*32 + rr)*Ktot + k0 + seg);
  };
  loadAB(0);
  for (int k0=0; k0<Ktot; k0+=64){
    __syncthreads();
    #pragma unroll
    for (int p=0;p<2;p++) *(int4*)&As[p*32+rr][seg] = ra[p];
    #pragma unroll
    for (int p=0;p<4;p++) *(int4*)&Bs[p*32+rr][seg] = rb[p];
    __syncthreads();
    if (k0+64 < Ktot) loadAB(k0+64);   // prefetch; regs free (already stored)
    #pragma unroll
    for (int kk=0;kk<2;kk++){
      bf16x8 af = *(bf16x8*)&As[wave*16 + l16][kk*32 + quad*8];
      #pragma unroll
      for (int nf=0;nf<8;nf++){
        bf16x8 bfv = *(bf16x8*)&Bs[nf*16 + l16][kk*32 + quad*8];
        acc[nf] = __builtin_amdgcn_mfma_f32_16x16x32_bf16(af, bfv, acc[nf], 0,0,0);
      }
    }
  }
  // ---- fused sd: partial <h,a> dots from exact fp32 acc ----
  float av[8], bv[8];
  #pragma unroll
  for (int nf=0;nf<8;nf++){
    int c = bn + nf*16 + l16;
    av[nf] = asrc[c];
    bv[nf] = adst[c];
  }
  #pragma unroll
  for (int r=0;r<4;r++){
    int row = bm + wave*16 + quad*4 + r;
    float psA=0.f, pdA=0.f, psB=0.f, pdB=0.f;
    #pragma unroll
    for (int nf=0;nf<4;nf++){ psA += acc[nf][r]*av[nf]; pdA += acc[nf][r]*bv[nf]; }
    #pragma unroll
    for (int nf=4;nf<8;nf++){ psB += acc[nf][r]*av[nf]; pdB += acc[nf][r]*bv[nf]; }
    #pragma unroll
    for (int off=1; off<16; off<<=1){
      psA += __shfl_xor(psA,off); pdA += __shfl_xor(pdA,off);
      psB += __shfl_xor(psB,off); pdB += __shfl_xor(pdB,off);
    }
    if (l16==0 && row < M){
      if (H == 4){
        int h0 = bn>>6;
        atomicAdd(&sv[row*4 + h0],     psA);
        atomicAdd(&dv[row*4 + h0],     pdA);
        atomicAdd(&sv[row*4 + h0 + 1], psB);
        atomicAdd(&dv[row*4 + h0 + 1], pdB);
      } else {
        atomicAdd(&sv[row], psA + psB);
        atomicAdd(&dv[row], pdA + pdB);
      }
    }
  }
  // ---- coalesced bf16 epilogue: quad stages+writes its own row ----
  __syncthreads();                       // all frag reads done; reuse As
  unsigned short* stgS = (unsigned short*)(&As[0][0]) + wave*1056; // 4 x 264
  #pragma unroll
  for (int r=0;r<4;r++){
    #pragma unroll
    for (int nf=0;nf<8;nf++)
      stgS[quad*264 + nf*16 + l16] = bf16of(acc[nf][r]);   // row quad*4+r
    int row = bm + wave*16 + quad*4 + r;
    if (row < M){
      int4 v = *(int4*)(stgS + quad*264 + l16*8);          // 8 shorts/lane
      *(int4*)(Cb16 + (size_t)row*N + bn + l16*8) = v;     // 16 lanes = 256B
    }
  }
}

// ================= GAT aggregation: 64-ch slices, 16 lanes/node =============
template<int H, int C, bool SPLIT>
__global__ __launch_bounds__(256) void agg_kernel(
    const unsigned short* __restrict__ hb, const float* __restrict__ s,
    const float* __restrict__ d, const int* __restrict__ offs,
    const int* __restrict__ csr, const float* __restrict__ bias,
    float* __restrict__ yf, unsigned short* __restrict__ ys, int n_nodes){
  constexpr int HC = H*C;
  constexpr int SLICES = HC/64;        // 4 (HC=256) or 2 (HC=128)
  int bx = blockIdx.x;
  int sl = bx % SLICES;
  int ng = bx / SLICES;
  int tid = threadIdx.x;
  int grp = tid >> 4;                  // node within the 16-node group
  int l4  = tid & 15;                  // lane within node
  int n = ng*16 + grp;
  if (n >= n_nodes) return;
  int c0 = sl*64 + l4*4;               // 4 channels per lane
  int head = c0 / C;                   // uniform per group (C=64: head=sl)
  float ddst = d[n*H + head];
  int start = offs[n];
  int cnt = offs[n+1] - start;
  int cnt1 = cnt + 1;                  // + self loop
  float a0=0.f, a1=0.f, a2=0.f, a3=0.f, lp=0.f;
  for (int base=0; base<cnt1; base+=16){
    int nchunk = min(16, cnt1-base);
    int srcv = 0; float wv = 0.f;
    if (l4 < nchunk){
      int i = base + l4;
      srcv = (i==cnt) ? n : csr[start+i];
      float e = s[srcv*H + head] + ddst;
      e = e>=0.f ? e : NEG_SLOPE*e;
      wv = expf(e);
      lp += wv;
    }
    for (int j=0;j<nchunk;j++){
      int sj = __shfl(srcv, j, 16);
      float wj = __shfl(wv, j, 16);
      int2 hv = *reinterpret_cast<const int2*>(hb + (size_t)sj*HC + c0);
      a0 += wj*bf2f((unsigned)hv.x & 0xFFFFu);
      a1 += wj*bf2f((unsigned)hv.x >> 16);
      a2 += wj*bf2f((unsigned)hv.y & 0xFFFFu);
      a3 += wj*bf2f((unsigned)hv.y >> 16);
    }
  }
  #pragma unroll
  for (int off=1; off<16; off<<=1) lp += __shfl_xor(lp, off, 16);
  float inv = 1.f/(lp + 1e-16f);
  float o[4] = {a0*inv, a1*inv, a2*inv, a3*inv};
  #pragma unroll
  for (int v=0;v<4;v++){
    float t = o[v] + bias[c0+v];
    o[v] = t>0.f ? t : expm1f(t);
  }
  if (SPLIT){
    unsigned u0 = (unsigned)bf16of(o[0]) | ((unsigned)bf16of(o[1])<<16);
    unsigned u1 = (unsigned)bf16of(o[2]) | ((unsigned)bf16of(o[3])<<16);
    *reinterpret_cast<uint2*>(ys + (size_t)n*HC + c0) = make_uint2(u0,u1);
  } else {
    float4 fv = make_float4(o[0], o[1], o[2], o[3]);
    *reinterpret_cast<float4*>(yf + (size_t)n*HC + c0) = fv;
  }
}

// ============ Set2Set (all 3 steps) + scorer, one block per graph ===========
// Set2Set decomposes fully per graph (h,c,qstar,e,r are per-graph) - no
// cross-graph dependency, so the whole chain runs in one kernel with block-
// local barriers. Memory patterns fixed vs r3's version: e-phase is one wave
// per node (float2 coalesced + shfl), r-phase is 128-col x 2-row register
// accumulation over coalesced 512B rows. LSTM/scorer weights are L3-resident
// (all 64 blocks read the same 768KB).
__global__ __launch_bounds__(256) void s2s_all_kernel(
    const float* __restrict__ x, const int* __restrict__ gstart,
    const int* __restrict__ gend, float* __restrict__ e_ws,
    const float* __restrict__ Wih, const float* __restrict__ Whh,
    const float* __restrict__ bih, const float* __restrict__ bhh,
    const float* __restrict__ gfeat,
    const float* __restrict__ gW1, const float* __restrict__ gb1,
    const float* __restrict__ gW2, const float* __restrict__ gb2,
    const float* __restrict__ mW1, const float* __restrict__ mb1,
    const float* __restrict__ mW2, const float* __restrict__ mb2,
    float* __restrict__ out){
  int b = blockIdx.x, tid = threadIdx.x;
  int wave = tid>>6, lane = tid&63;
  __shared__ float qs[256], hs[128], cs[128], gsh[512], red[256], lsh[2];
  int start = gstart[b], end = gend[b];
  if (tid < 128){ hs[tid]=0.f; cs[tid]=0.f; }
  qs[tid] = 0.f;
  __syncthreads();
  for (int step=0; step<3; ++step){
    // ---- LSTM gates ----
    #pragma unroll
    for (int p=0;p<2;p++){
      int j = tid + p*256;
      float a = bih[j] + bhh[j];
      if (step > 0){
        const float* wi = Wih + (size_t)j*256;
        for (int k=0;k<256;k+=4)
          a += qs[k]*wi[k] + qs[k+1]*wi[k+1] + qs[k+2]*wi[k+2] + qs[k+3]*wi[k+3];
        const float* wh = Whh + (size_t)j*128;
        for (int k=0;k<128;k+=4)
          a += hs[k]*wh[k] + hs[k+1]*wh[k+1] + hs[k+2]*wh[k+2] + hs[k+3]*wh[k+3];
      }
      gsh[j] = a;
    }
    __syncthreads();
    if (tid < 128){
      float ig = sigmoidf(gsh[tid]);
      float fg = sigmoidf(gsh[128+tid]);
      float gg = tanhf(gsh[256+tid]);
      float og = sigmoidf(gsh[384+tid]);
      float c2 = fg*cs[tid] + ig*gg;
      cs[tid] = c2;
      hs[tid] = og*tanhf(c2);
    }
    __syncthreads();
    // ---- e phase: w_i = exp(<x_i, q>), one wave per node ----
    float q0 = hs[lane*2], q1 = hs[lane*2+1];
    for (int i = start + wave; i < end; i += 4){
      float2 xv = *reinterpret_cast<const float2*>(x + (size_t)i*128 + lane*2);
      float p = xv.x*q0 + xv.y*q1;
      #pragma unroll
      for (int off=32; off; off>>=1) p += __shfl_down(p, off);
      if (lane==0) e_ws[i] = expf(p);
    }
    __syncthreads();
    // ---- r phase: 128 cols x 2 nodes, register accumulation ----
    int half = tid >> 7, col = tid & 127;
    float rc = 0.f, ls = 0.f;
    #pragma unroll 4
    for (int i=start+half; i<end; i+=2){
      float w = e_ws[i];
      rc += w * x[(size_t)i*128+col];
      if (col==0) ls += w;
    }
    if (tid < 2) lsh[tid]=0.f;
    __syncthreads();
    red[tid] = rc;
    if (col==0) lsh[half] = ls;
    __syncthreads();
    if (tid < 128){
      float r = (red[tid]+red[tid+128])/(lsh[0]+lsh[1]+1e-16f);
      qs[tid]     = hs[tid];
      qs[128+tid] = r;
    }
    __syncthreads();
  }
  // ---- scorer: z = [qstar, gf-MLP]; out = relu(z@mW1+mb1)@mW2+mb2 ----
  __shared__ float z[288], gf1[64], hid[128];
  z[tid] = qs[tid];
  if (tid < 64){
    float a = gb1[tid];
    for (int k=0;k<9;k++) a += gfeat[b*9+k]*gW1[k*64+tid];
    gf1[tid] = a>0.f ? a : 0.f;
  }
  __syncthreads();
  if (tid < 32){
    float a = gb2[tid];
    for (int k=0;k<64;k++) a += gf1[k]*gW2[k*32+tid];
    z[256+tid] = a;
  }
  __syncthreads();
  if (tid < 128){
    float a = mb1[tid];
    for (int k=0;k<288;k++) a += z[k]*mW1[(size_t)k*128+tid];
    hid[tid] = a>0.f ? a : 0.f;
  }
  __syncthreads();
  if (tid < 4){
    float a = mb2[tid];
    for (int k=0;k<128;k++) a += hid[k]*mW2[k*4+tid];
    out[b*4+tid] = a;
  }
}

// ================================ launch ====================================
extern "C" void kernel_launch(void* const* d_in, const int* in_sizes, int n_in,
                              void* d_out, int out_size, void* d_ws, size_t ws_size,
                              hipStream_t stream) {
  const float* x     = (const float*)d_in[0];
  const int*   ei    = (const int*)d_in[1];
  const int*   batch = (const int*)d_in[2];
  const float* gfeat = (const float*)d_in[3];
  const float* W1    = (const float*)d_in[4];
  const float* as1   = (const float*)d_in[5];
  const float* ad1   = (const float*)d_in[6];
  const float* b1    = (const float*)d_in[7];
  const float* W2    = (const float*)d_in[8];
  const float* as2   = (const float*)d_in[9];
  const float* ad2   = (const float*)d_in[10];
  const float* b2    = (const float*)d_in[11];
  const float* W3    = (const float*)d_in[12];
  const float* as3   = (const float*)d_in[13];
  const float* ad3   = (const float*)d_in[14];
  const float* b3    = (const float*)d_in[15];
  const float* Wih   = (const float*)d_in[16];
  const float* Whh   = (const float*)d_in[17];
  const float* bih   = (const float*)d_in[18];
  const float* bhh   = (const float*)d_in[19];
  const float* gW1   = (const float*)d_in[20];
  const float* gb1   = (const float*)d_in[21];
  const float* gW2   = (const float*)d_in[22];
  const float* gb2   = (const float*)d_in[23];
  const float* mW1   = (const float*)d_in[24];
  const float* mb1   = (const float*)d_in[25];
  const float* mW2   = (const float*)d_in[26];
  const float* mb2   = (const float*)d_in[27];

  const int N = in_sizes[0]/128;   // 20000
  const int E = in_sizes[1]/2;     // 320000
  const int B = in_sizes[3]/9;     // 64
  const int Mpad = ((N + 127)/128)*128;   // 20096

  char* ws = (char*)d_ws;
  size_t off = 0;
  auto alloc = [&](size_t bytes)->char*{
    char* p = ws + off;
    off += (bytes + 255) & ~(size_t)255;
    return p;
  };
  unsigned short* hb16 = (unsigned short*)alloc((size_t)N*256*2);   // bf16 h
  unsigned short* y1   = (unsigned short*)alloc((size_t)Mpad*256*2);// bf16 y1
  unsigned short* y2   = (unsigned short*)alloc((size_t)Mpad*256*2);// bf16 y2
  float*    ybuf    = (float*)alloc((size_t)N*128*4);
  unsigned short* WT1 = (unsigned short*)alloc((size_t)256*128*2);
  unsigned short* WT2 = (unsigned short*)alloc((size_t)256*256*2);
  unsigned short* WT3 = (unsigned short*)alloc((size_t)128*256*2);
  float* sdbuf  = (float*)alloc((size_t)18*N*4);   // s1 d1 s2 d2 s3 d3
  float* e_ws   = (float*)alloc((size_t)N*4);
  int*   counts = (int*)alloc((size_t)N*4);
  int*   offs   = (int*)alloc((size_t)(N+1)*4);
  int*   cursor = (int*)alloc((size_t)N*4);
  int*   csr    = (int*)alloc((size_t)E*4);
  int*   gstart = (int*)alloc((size_t)B*4);
  int*   gend   = (int*)alloc((size_t)B*4);

  float* s1 = sdbuf;            float* d1 = sdbuf + (size_t)4*N;
  float* s2 = sdbuf + (size_t)8*N;  float* d2 = sdbuf + (size_t)12*N;
  float* s3 = sdbuf + (size_t)16*N; float* d3 = sdbuf + (size_t)17*N;

  int npadints = (Mpad - N)*128;
  int nInit = 18*N;
  if (npadints > nInit) nInit = npadints;
  if (256*256 > nInit) nInit = 256*256;
  init_kernel<<<(nInit+255)/256, 256, 0, stream>>>(counts, gstart, gend, sdbuf,
      (int*)(y1 + (size_t)N*256), (int*)(y2 + (size_t)N*256),
      npadints, W1, WT1, W2, WT2, W3, WT3, N, B);
  int gridEN = (max(E,N)+255)/256;
  build_kernel<<<gridEN, 256, 0, stream>>>(ei, batch, counts, gstart, gend, E, N);
  scan_kernel<<<1, 1024, 0, stream>>>(counts, offs, cursor, N);
  fill_kernel<<<(E+255)/256, 256, 0, stream>>>(ei, cursor, csr, E);

  int gm = Mpad/64;
  int ng16 = (N+15)/16;
  // ---- layer 1: x (fp32->bf16 inline, K=128) -> h bf16 + s1,d1 -> y1
  gemm_bf16<true,4><<<dim3(2,gm), 256, 0, stream>>>((const void*)x, (const short*)WT1,
      hb16, as1, ad1, s1, d1, N, 128, 256);
  agg_kernel<4,64,true><<<ng16*4, 256, 0, stream>>>(hb16, s1, d1, offs, csr, b1, nullptr, y1, N);
  // ---- layer 2: y1 (bf16, K=256) -> h bf16 + s2,d2 -> y2
  gemm_bf16<false,4><<<dim3(2,gm), 256, 0, stream>>>((const void*)y1, (const short*)WT2,
      hb16, as2, ad2, s2, d2, N, 256, 256);
  agg_kernel<4,64,true><<<ng16*4, 256, 0, stream>>>(hb16, s2, d2, offs, csr, b2, nullptr, y2, N);
  // ---- layer 3: y2 (bf16, K=256) -> h bf16 [N,128] + s3,d3 -> ybuf (fp32)
  gemm_bf16<false,1><<<dim3(1,gm), 256, 0, stream>>>((const void*)y2, (const short*)WT3,
      hb16, as3, ad3, s3, d3, N, 256, 128);
  agg_kernel<1,128,false><<<ng16*2, 256, 0, stream>>>(hb16, s3, d3, offs, csr, b3, ybuf, nullptr, N);

  // ---- set2set (all steps) + scorer: one kernel, one block per graph ----
  s2s_all_kernel<<<B, 256, 0, stream>>>(ybuf, gstart, gend, e_ws,
      Wih, Whh, bih, bhh, gfeat, gW1, gb1, gW2, gb2, mW1, mb1, mW2, mb2,
      (float*)d_out);
}

// Round 17
// 453.446 us; speedup vs baseline: 1.1618x; 1.1618x over previous
//
#include <hip/hip_runtime.h>
#include <hip/hip_bf16.h>
#include <math.h>

#define NEG_SLOPE 0.2f

typedef __attribute__((ext_vector_type(8))) short bf16x8;
typedef __attribute__((ext_vector_type(4))) float f32x4;

__device__ __forceinline__ float sigmoidf(float x){ return 1.f/(1.f+expf(-x)); }
__device__ __forceinline__ float bf2f(unsigned us){ return __uint_as_float(us << 16); }
__device__ __forceinline__ unsigned short bf16of(float v){
  __hip_bfloat16 h = __float2bfloat16(v);
  return __builtin_bit_cast(unsigned short, h);
}

// ============== init + CSR prep + weight packing (one launch) ===============
// Weights packed PLAIN bf16, transposed: WT[N][K]. (r14 audit: split-K
// interleave computed hi*hi + lo*lo - missing hi*lo cross terms = plain-bf16
// accuracy at 2x cost; r15 verified absmax unchanged at half the traffic.)
__global__ void init_kernel(int* counts, int* gstart, int* gend,
                            float* rsum, float* lsum, float* sdbuf,
                            int* pad1, int* pad2, int npadints,
                            const float* __restrict__ W1, unsigned short* __restrict__ WT1,
                            const float* __restrict__ W2, unsigned short* __restrict__ WT2,
                            const float* __restrict__ W3, unsigned short* __restrict__ WT3,
                            int n, int b){
  int i = blockIdx.x*blockDim.x + threadIdx.x;
  if (i < n) counts[i] = 0;
  if (i < b){ gstart[i] = 0; gend[i] = 0; }
  if (i < 3*b*128) rsum[i] = 0.f;
  if (i < 3*b) lsum[i] = 0.f;
  if (i < 18*n) sdbuf[i] = 0.f;
  if (i < npadints){ pad1[i] = 0; pad2[i] = 0; }
  if (i < 128*256){                 // W1 [128,256] -> WT1 [256][128]
    int k = i>>8, c = i&255;
    WT1[(size_t)c*128 + k] = bf16of(W1[i]);
  }
  if (i < 256*256){                 // W2 [256,256] -> WT2 [256][256]
    int k = i>>8, c = i&255;
    WT2[(size_t)c*256 + k] = bf16of(W2[i]);
  }
  if (i < 256*128){                 // W3 [256,128] -> WT3 [128][256]
    int k = i>>7, c = i&127;
    WT3[(size_t)c*256 + k] = bf16of(W3[i]);
  }
}

__global__ void build_kernel(const int* __restrict__ ei, const int* __restrict__ batch,
                             int* counts, int* gstart, int* gend, int E, int n){
  int i = blockIdx.x*blockDim.x + threadIdx.x;
  if (i < E) atomicAdd(&counts[ei[E+i]], 1);
  if (i < n){
    int b = batch[i];
    if (i == 0 || batch[i-1] != b) gstart[b] = i;
    if (i == n-1 || batch[i+1] != b) gend[b] = i+1;
  }
}

__global__ void scan_kernel(const int* __restrict__ counts, int* offs, int* cursor, int n){
  const int T = 1024;
  int tid = threadIdx.x;
  int chunk = (n + T - 1)/T;
  int base = tid*chunk;
  int local = 0;
  for (int i=0;i<chunk;i++){ int idx=base+i; if (idx<n) local += counts[idx]; }
  __shared__ int ss[T];
  ss[tid]=local; __syncthreads();
  for (int off=1; off<T; off<<=1){
    int v = (tid>=off)? ss[tid-off] : 0;
    __syncthreads();
    ss[tid]+=v;
    __syncthreads();
  }
  int run = ss[tid]-local;
  for (int i=0;i<chunk;i++){
    int idx=base+i;
    if (idx<n){ offs[idx]=run; cursor[idx]=run; run += counts[idx]; }
  }
  if (tid==T-1) offs[n]=run;
}

__global__ void fill_kernel(const int* __restrict__ ei, int* cursor, int* csr, int E){
  int i = blockIdx.x*blockDim.x + threadIdx.x;
  if (i<E){
    int dst = ei[E+i];
    int pos = atomicAdd(&cursor[dst],1);
    csr[pos] = ei[i];
  }
}

// ========================= plain-bf16 MFMA GEMM =============================
// C[M,N] = A[Mpad,K] x BT[N,K]^T, bf16 in, bf16 out (hb16) + fused s,d.
// AF32: A is fp32 [M,K], converted to bf16 inline during staging.
// Register-prefetch double buffer; LDS-staged coalesced bf16 epilogue.
template<bool AF32, int H>
__global__ __launch_bounds__(256) void gemm_bf16(
    const void* __restrict__ Aptr, const short* __restrict__ BT,
    unsigned short* __restrict__ Cb16,
    const float* __restrict__ asrc, const float* __restrict__ adst,
    float* __restrict__ sv, float* __restrict__ dv,
    int M, int Ktot, int N){
  __shared__ short As[64][72];
  __shared__ short Bs[128][72];
  int tid = threadIdx.x;
  int wave = tid>>6, lane = tid&63;
  int quad = lane>>4, l16 = lane&15;
  int bm = blockIdx.y*64, bn = blockIdx.x*128;
  f32x4 acc[8];
  #pragma unroll
  for (int i=0;i<8;i++) acc[i] = (f32x4){0.f,0.f,0.f,0.f};
  int rr = tid>>3;          // 0..31
  int seg = (tid&7)*8;      // shorts (= bf16 elements = k index)
  int4 ra[2], rb[4];
  auto loadAB = [&](int k0){
    if (AF32){
      const float* A = (const float*)Aptr;
      #pragma unroll
      for (int p=0;p<2;p++){
        int row = bm + p*32 + rr;
        float4 v0 = make_float4(0.f,0.f,0.f,0.f), v1 = v0;
        if (row < M){
          const float* ap = A + (size_t)row*Ktot + k0 + seg;
          v0 = *(const float4*)(ap);
          v1 = *(const float4*)(ap+4);
        }
        unsigned u0 = (unsigned)bf16of(v0.x) | ((unsigned)bf16of(v0.y)<<16);
        unsigned u1 = (unsigned)bf16of(v0.z) | ((unsigned)bf16of(v0.w)<<16);
        unsigned u2 = (unsigned)bf16of(v1.x) | ((unsigned)bf16of(v1.y)<<16);
        unsigned u3 = (unsigned)bf16of(v1.z) | ((unsigned)bf16of(v1.w)<<16);
        ra[p] = make_int4((int)u0,(int)u1,(int)u2,(int)u3);
      }
    } else {
      const short* A = (const short*)Aptr;
      #pragma unroll
      for (int p=0;p<2;p++)
        ra[p] = *(const int4*)(A + (size_t)(bm + p*32 + rr)*Ktot + k0 + seg);
    }
    #pragma unroll
    for (int p=0;p<4;p++)
      rb[p] = *(const int4*)(BT + (size_t)(bn + p*32 + rr)*Ktot + k0 + seg);
  };
  loadAB(0);
  for (int k0=0; k0<Ktot; k0+=64){
    __syncthreads();
    #pragma unroll
    for (int p=0;p<2;p++) *(int4*)&As[p*32+rr][seg] = ra[p];
    #pragma unroll
    for (int p=0;p<4;p++) *(int4*)&Bs[p*32+rr][seg] = rb[p];
    __syncthreads();
    if (k0+64 < Ktot) loadAB(k0+64);   // prefetch; regs free (already stored)
    #pragma unroll
    for (int kk=0;kk<2;kk++){
      bf16x8 af = *(bf16x8*)&As[wave*16 + l16][kk*32 + quad*8];
      #pragma unroll
      for (int nf=0;nf<8;nf++){
        bf16x8 bfv = *(bf16x8*)&Bs[nf*16 + l16][kk*32 + quad*8];
        acc[nf] = __builtin_amdgcn_mfma_f32_16x16x32_bf16(af, bfv, acc[nf], 0,0,0);
      }
    }
  }
  // ---- fused sd: partial <h,a> dots from exact fp32 acc ----
  float av[8], bv[8];
  #pragma unroll
  for (int nf=0;nf<8;nf++){
    int c = bn + nf*16 + l16;
    av[nf] = asrc[c];
    bv[nf] = adst[c];
  }
  #pragma unroll
  for (int r=0;r<4;r++){
    int row = bm + wave*16 + quad*4 + r;
    float psA=0.f, pdA=0.f, psB=0.f, pdB=0.f;
    #pragma unroll
    for (int nf=0;nf<4;nf++){ psA += acc[nf][r]*av[nf]; pdA += acc[nf][r]*bv[nf]; }
    #pragma unroll
    for (int nf=4;nf<8;nf++){ psB += acc[nf][r]*av[nf]; pdB += acc[nf][r]*bv[nf]; }
    #pragma unroll
    for (int off=1; off<16; off<<=1){
      psA += __shfl_xor(psA,off); pdA += __shfl_xor(pdA,off);
      psB += __shfl_xor(psB,off); pdB += __shfl_xor(pdB,off);
    }
    if (l16==0 && row < M){
      if (H == 4){
        int h0 = bn>>6;
        atomicAdd(&sv[row*4 + h0],     psA);
        atomicAdd(&dv[row*4 + h0],     pdA);
        atomicAdd(&sv[row*4 + h0 + 1], psB);
        atomicAdd(&dv[row*4 + h0 + 1], pdB);
      } else {
        atomicAdd(&sv[row], psA + psB);
        atomicAdd(&dv[row], pdA + pdB);
      }
    }
  }
  // ---- coalesced bf16 epilogue: quad stages+writes its own row ----
  // C/D layout: col=lane&15, row=quad*4+reg (m89/m91 verified)
  __syncthreads();                       // all frag reads done; reuse As
  unsigned short* stgS = (unsigned short*)(&As[0][0]) + wave*1056; // 4 x 264
  #pragma unroll
  for (int r=0;r<4;r++){
    #pragma unroll
    for (int nf=0;nf<8;nf++)
      stgS[quad*264 + nf*16 + l16] = bf16of(acc[nf][r]);   // row quad*4+r
    int row = bm + wave*16 + quad*4 + r;
    if (row < M){
      int4 v = *(int4*)(stgS + quad*264 + l16*8);          // 8 shorts/lane
      *(int4*)(Cb16 + (size_t)row*N + bn + l16*8) = v;     // 16 lanes = 256B
    }
  }
}

// ================= GAT aggregation: 64-ch slices, 16 lanes/node =============
// slice = bx % SLICES pins a 64-channel slice to an XCD (r13/r14-validated:
// FETCH 151->18.5 MB, issue-width restored by int2 gathers).
template<int H, int C, bool SPLIT>
__global__ __launch_bounds__(256) void agg_kernel(
    const unsigned short* __restrict__ hb, const float* __restrict__ s,
    const float* __restrict__ d, const int* __restrict__ offs,
    const int* __restrict__ csr, const float* __restrict__ bias,
    float* __restrict__ yf, unsigned short* __restrict__ ys, int n_nodes){
  constexpr int HC = H*C;
  constexpr int SLICES = HC/64;        // 4 (HC=256) or 2 (HC=128)
  int bx = blockIdx.x;
  int sl = bx % SLICES;
  int ng = bx / SLICES;
  int tid = threadIdx.x;
  int grp = tid >> 4;                  // node within the 16-node group
  int l4  = tid & 15;                  // lane within node
  int n = ng*16 + grp;
  if (n >= n_nodes) return;
  int c0 = sl*64 + l4*4;               // 4 channels per lane
  int head = c0 / C;                   // uniform per group (C=64: head=sl)
  float ddst = d[n*H + head];
  int start = offs[n];
  int cnt = offs[n+1] - start;
  int cnt1 = cnt + 1;                  // + self loop
  float a0=0.f, a1=0.f, a2=0.f, a3=0.f, lp=0.f;
  for (int base=0; base<cnt1; base+=16){
    int nchunk = min(16, cnt1-base);
    int srcv = 0; float wv = 0.f;
    if (l4 < nchunk){
      int i = base + l4;
      srcv = (i==cnt) ? n : csr[start+i];
      float e = s[srcv*H + head] + ddst;
      e = e>=0.f ? e : NEG_SLOPE*e;
      wv = expf(e);
      lp += wv;
    }
    for (int j=0;j<nchunk;j++){
      int sj = __shfl(srcv, j, 16);
      float wj = __shfl(wv, j, 16);
      int2 hv = *reinterpret_cast<const int2*>(hb + (size_t)sj*HC + c0);
      a0 += wj*bf2f((unsigned)hv.x & 0xFFFFu);
      a1 += wj*bf2f((unsigned)hv.x >> 16);
      a2 += wj*bf2f((unsigned)hv.y & 0xFFFFu);
      a3 += wj*bf2f((unsigned)hv.y >> 16);
    }
  }
  #pragma unroll
  for (int off=1; off<16; off<<=1) lp += __shfl_xor(lp, off, 16);
  float inv = 1.f/(lp + 1e-16f);
  float o[4] = {a0*inv, a1*inv, a2*inv, a3*inv};
  #pragma unroll
  for (int v=0;v<4;v++){
    float t = o[v] + bias[c0+v];
    o[v] = t>0.f ? t : expm1f(t);
  }
  if (SPLIT){
    unsigned u0 = (unsigned)bf16of(o[0]) | ((unsigned)bf16of(o[1])<<16);
    unsigned u1 = (unsigned)bf16of(o[2]) | ((unsigned)bf16of(o[3])<<16);
    *reinterpret_cast<uint2*>(ys + (size_t)n*HC + c0) = make_uint2(u0,u1);
  } else {
    float4 fv = make_float4(o[0], o[1], o[2], o[3]);
    *reinterpret_cast<float4*>(yf + (size_t)n*HC + c0) = fv;
  }
}

// ======================= Set2Set, grid-parallel =============================
// (r16 lesson, twice-learned: the node-dim work MUST be grid-parallel; the
// 64-block fused variant was 189us at 2.6% occupancy.)
__global__ __launch_bounds__(256) void read_kernel(
    const float* __restrict__ x, const float* __restrict__ q,
    const int* __restrict__ batch,
    float* __restrict__ rsum, float* __restrict__ lsum, int N){
  int tid = threadIdx.x;
  int wave = tid>>6, lane = tid&63;
  int c0 = blockIdx.x*32;
  if (c0 >= N) return;
  __shared__ float ws[32];
  __shared__ int gb[32];
  if (tid < 32 && c0+tid < N) gb[tid] = batch[c0+tid];
  __syncthreads();
  #pragma unroll
  for (int j=0;j<8;j++){
    int k = wave*8 + j;
    int i = c0 + k;
    if (i < N){
      int g = gb[k];
      float2 xv = *reinterpret_cast<const float2*>(x + (size_t)i*128 + lane*2);
      float2 qv = *reinterpret_cast<const float2*>(q + (size_t)g*128 + lane*2);
      float p = xv.x*qv.x + xv.y*qv.y;
      #pragma unroll
      for (int off=32; off; off>>=1) p += __shfl_down(p, off);
      if (lane==0) ws[k] = expf(p);
    }
  }
  __syncthreads();
  if (tid < 128){
    int col = tid;
    int endi = min(c0+32, N);
    int curg = gb[0];
    float acc = 0.f, lacc = 0.f;
    for (int i=c0; i<endi; ++i){
      int g = gb[i-c0];
      if (g != curg){
        atomicAdd(&rsum[curg*128+col], acc);
        if (col==0) atomicAdd(&lsum[curg], lacc);
        acc = 0.f; lacc = 0.f; curg = g;
      }
      float w = ws[i-c0];
      acc += w * x[(size_t)i*128+col];
      lacc += w;
    }
    atomicAdd(&rsum[curg*128+col], acc);
    if (col==0) atomicAdd(&lsum[curg], lacc);
  }
}

template<int STEP>
__global__ __launch_bounds__(256) void s2s_step_kernel(
    const float* __restrict__ rsum, const float* __restrict__ lsum,
    float* __restrict__ hc, float* __restrict__ qbuf,
    const float* __restrict__ Wih, const float* __restrict__ Whh,
    const float* __restrict__ bih, const float* __restrict__ bhh,
    const float* __restrict__ gfeat,
    const float* __restrict__ gW1, const float* __restrict__ gb1,
    const float* __restrict__ gW2, const float* __restrict__ gb2,
    const float* __restrict__ mW1, const float* __restrict__ mb1,
    const float* __restrict__ mW2, const float* __restrict__ mb2,
    float* __restrict__ out, int B){
  int b = blockIdx.x, tid = threadIdx.x;
  __shared__ float qs[256];

  if (STEP > 0){
    if (tid < 128){
      const float* rs = rsum + (size_t)(STEP-1)*B*128 + (size_t)b*128;
      float ls = lsum[(STEP-1)*B + b];
      qs[tid]     = qbuf[b*128+tid];
      qs[128+tid] = rs[tid] / (ls + 1e-16f);
    }
    __syncthreads();
  }

  if (STEP < 3){
    __shared__ float hs[128], gsh[512];
    if (STEP > 0){ if (tid<128) hs[tid] = hc[(size_t)b*128+tid]; }
    __syncthreads();
    #pragma unroll
    for (int p=0;p<2;p++){
      int j = tid + p*256;
      float a = bih[j] + bhh[j];
      if (STEP > 0){
        const float* wi = Wih + (size_t)j*256;
        for (int k=0;k<256;k+=4)
          a += qs[k]*wi[k] + qs[k+1]*wi[k+1] + qs[k+2]*wi[k+2] + qs[k+3]*wi[k+3];
        const float* wh = Whh + (size_t)j*128;
        for (int k=0;k<128;k+=4)
          a += hs[k]*wh[k] + hs[k+1]*wh[k+1] + hs[k+2]*wh[k+2] + hs[k+3]*wh[k+3];
      }
      gsh[j] = a;
    }
    __syncthreads();
    if (tid < 128){
      float cprev = (STEP==0) ? 0.f : hc[(size_t)(B+b)*128+tid];
      float ig = sigmoidf(gsh[tid]);
      float fg = sigmoidf(gsh[128+tid]);
      float gg = tanhf(gsh[256+tid]);
      float og = sigmoidf(gsh[384+tid]);
      float c2 = fg*cprev + ig*gg;
      float h2 = og*tanhf(c2);
      hc[(size_t)b*128+tid] = h2;
      hc[(size_t)(B+b)*128+tid] = c2;
      qbuf[b*128+tid] = h2;
    }
  } else {
    __shared__ float z[288], gf1[64], hid[128];
    z[tid] = qs[tid];
    if (tid < 64){
      float a = gb1[tid];
      for (int k=0;k<9;k++) a += gfeat[b*9+k]*gW1[k*64+tid];
      gf1[tid] = a>0.f ? a : 0.f;
    }
    __syncthreads();
    if (tid < 32){
      float a = gb2[tid];
      for (int k=0;k<64;k++) a += gf1[k]*gW2[k*32+tid];
      z[256+tid] = a;
    }
    __syncthreads();
    if (tid < 128){
      float a = mb1[tid];
      for (int k=0;k<288;k++) a += z[k]*mW1[(size_t)k*128+tid];
      hid[tid] = a>0.f ? a : 0.f;
    }
    __syncthreads();
    if (tid < 4){
      float a = mb2[tid];
      for (int k=0;k<128;k++) a += hid[k]*mW2[k*4+tid];
      out[b*4+tid] = a;
    }
  }
}

// ================================ launch ====================================
extern "C" void kernel_launch(void* const* d_in, const int* in_sizes, int n_in,
                              void* d_out, int out_size, void* d_ws, size_t ws_size,
                              hipStream_t stream) {
  const float* x     = (const float*)d_in[0];
  const int*   ei    = (const int*)d_in[1];
  const int*   batch = (const int*)d_in[2];
  const float* gfeat = (const float*)d_in[3];
  const float* W1    = (const float*)d_in[4];
  const float* as1   = (const float*)d_in[5];
  const float* ad1   = (const float*)d_in[6];
  const float* b1    = (const float*)d_in[7];
  const float* W2    = (const float*)d_in[8];
  const float* as2   = (const float*)d_in[9];
  const float* ad2   = (const float*)d_in[10];
  const float* b2    = (const float*)d_in[11];
  const float* W3    = (const float*)d_in[12];
  const float* as3   = (const float*)d_in[13];
  const float* ad3   = (const float*)d_in[14];
  const float* b3    = (const float*)d_in[15];
  const float* Wih   = (const float*)d_in[16];
  const float* Whh   = (const float*)d_in[17];
  const float* bih   = (const float*)d_in[18];
  const float* bhh   = (const float*)d_in[19];
  const float* gW1   = (const float*)d_in[20];
  const float* gb1   = (const float*)d_in[21];
  const float* gW2   = (const float*)d_in[22];
  const float* gb2   = (const float*)d_in[23];
  const float* mW1   = (const float*)d_in[24];
  const float* mb1   = (const float*)d_in[25];
  const float* mW2   = (const float*)d_in[26];
  const float* mb2   = (const float*)d_in[27];

  const int N = in_sizes[0]/128;   // 20000
  const int E = in_sizes[1]/2;     // 320000
  const int B = in_sizes[3]/9;     // 64
  const int Mpad = ((N + 127)/128)*128;   // 20096

  char* ws = (char*)d_ws;
  size_t off = 0;
  auto alloc = [&](size_t bytes)->char*{
    char* p = ws + off;
    off += (bytes + 255) & ~(size_t)255;
    return p;
  };
  unsigned short* hb16 = (unsigned short*)alloc((size_t)N*256*2);   // bf16 h
  unsigned short* y1   = (unsigned short*)alloc((size_t)Mpad*256*2);// bf16 y1
  unsigned short* y2   = (unsigned short*)alloc((size_t)Mpad*256*2);// bf16 y2
  float*    ybuf    = (float*)alloc((size_t)N*128*4);
  unsigned short* WT1 = (unsigned short*)alloc((size_t)256*128*2);
  unsigned short* WT2 = (unsigned short*)alloc((size_t)256*256*2);
  unsigned short* WT3 = (unsigned short*)alloc((size_t)128*256*2);
  float* sdbuf  = (float*)alloc((size_t)18*N*4);   // s1 d1 s2 d2 s3 d3
  int*   counts = (int*)alloc((size_t)N*4);
  int*   offs   = (int*)alloc((size_t)(N+1)*4);
  int*   cursor = (int*)alloc((size_t)N*4);
  int*   csr    = (int*)alloc((size_t)E*4);
  int*   gstart = (int*)alloc((size_t)B*4);
  int*   gend   = (int*)alloc((size_t)B*4);
  float* hcbuf  = (float*)alloc((size_t)2*B*128*4);
  float* qbuf   = (float*)alloc((size_t)B*128*4);
  float* rsum   = (float*)alloc((size_t)3*B*128*4);
  float* lsum   = (float*)alloc((size_t)3*B*4);

  float* s1 = sdbuf;            float* d1 = sdbuf + (size_t)4*N;
  float* s2 = sdbuf + (size_t)8*N;  float* d2 = sdbuf + (size_t)12*N;
  float* s3 = sdbuf + (size_t)16*N; float* d3 = sdbuf + (size_t)17*N;

  int npadints = (Mpad - N)*128;   // pad rows x 256 shorts / 2 per int
  int nInit = 18*N;
  if (npadints > nInit) nInit = npadints;
  if (256*256 > nInit) nInit = 256*256;
  init_kernel<<<(nInit+255)/256, 256, 0, stream>>>(counts, gstart, gend,
      rsum, lsum, sdbuf,
      (int*)(y1 + (size_t)N*256), (int*)(y2 + (size_t)N*256),
      npadints, W1, WT1, W2, WT2, W3, WT3, N, B);
  int gridEN = (max(E,N)+255)/256;
  build_kernel<<<gridEN, 256, 0, stream>>>(ei, batch, counts, gstart, gend, E, N);
  scan_kernel<<<1, 1024, 0, stream>>>(counts, offs, cursor, N);
  fill_kernel<<<(E+255)/256, 256, 0, stream>>>(ei, cursor, csr, E);

  int gm = Mpad/64;
  int ng16 = (N+15)/16;
  // ---- layer 1: x (fp32->bf16 inline, K=128) -> h bf16 + s1,d1 -> y1
  gemm_bf16<true,4><<<dim3(2,gm), 256, 0, stream>>>((const void*)x, (const short*)WT1,
      hb16, as1, ad1, s1, d1, N, 128, 256);
  agg_kernel<4,64,true><<<ng16*4, 256, 0, stream>>>(hb16, s1, d1, offs, csr, b1, nullptr, y1, N);
  // ---- layer 2: y1 (bf16, K=256) -> h bf16 + s2,d2 -> y2
  gemm_bf16<false,4><<<dim3(2,gm), 256, 0, stream>>>((const void*)y1, (const short*)WT2,
      hb16, as2, ad2, s2, d2, N, 256, 256);
  agg_kernel<4,64,true><<<ng16*4, 256, 0, stream>>>(hb16, s2, d2, offs, csr, b2, nullptr, y2, N);
  // ---- layer 3: y2 (bf16, K=256) -> h bf16 [N,128] + s3,d3 -> ybuf (fp32)
  gemm_bf16<false,1><<<dim3(1,gm), 256, 0, stream>>>((const void*)y2, (const short*)WT3,
      hb16, as3, ad3, s3, d3, N, 256, 128);
  agg_kernel<1,128,false><<<ng16*2, 256, 0, stream>>>(hb16, s3, d3, offs, csr, b3, ybuf, nullptr, N);

  // ---- set2set (grid-parallel readout) + scorer ----
  int gr = (N+31)/32;
  s2s_step_kernel<0><<<B, 256, 0, stream>>>(rsum, lsum, hcbuf, qbuf,
      Wih, Whh, bih, bhh, gfeat, gW1, gb1, gW2, gb2, mW1, mb1, mW2, mb2, (float*)d_out, B);
  read_kernel<<<gr, 256, 0, stream>>>(ybuf, qbuf, batch, rsum + 0*(size_t)B*128, lsum + 0*B, N);
  s2s_step_kernel<1><<<B, 256, 0, stream>>>(rsum, lsum, hcbuf, qbuf,
      Wih, Whh, bih, bhh, gfeat, gW1, gb1, gW2, gb2, mW1, mb1, mW2, mb2, (float*)d_out, B);
  read_kernel<<<gr, 256, 0, stream>>>(ybuf, qbuf, batch, rsum + 1*(size_t)B*128, lsum + 1*B, N);
  s2s_step_kernel<2><<<B, 256, 0, stream>>>(rsum, lsum, hcbuf, qbuf,
      Wih, Whh, bih, bhh, gfeat, gW1, gb1, gW2, gb2, mW1, mb1, mW2, mb2, (float*)d_out, B);
  read_kernel<<<gr, 256, 0, stream>>>(ybuf, qbuf, batch, rsum + 2*(size_t)B*128, lsum + 2*B, N);
  s2s_step_kernel<3><<<B, 256, 0, stream>>>(rsum, lsum, hcbuf, qbuf,
      Wih, Whh, bih, bhh, gfeat, gW1, gb1, gW2, gb2, mW1, mb1, mW2, mb2, (float*)d_out, B);
}

// Round 18
// 450.987 us; speedup vs baseline: 1.1681x; 1.0055x over previous
//
#include <hip/hip_runtime.h>
#include <hip/hip_bf16.h>
#include <math.h>

#define NEG_SLOPE 0.2f

typedef __attribute__((ext_vector_type(8))) short bf16x8;
typedef __attribute__((ext_vector_type(4))) float f32x4;

__device__ __forceinline__ float sigmoidf(float x){ return 1.f/(1.f+expf(-x)); }
__device__ __forceinline__ float bf2f(unsigned us){ return __uint_as_float(us << 16); }
__device__ __forceinline__ unsigned short bf16of(float v){
  __hip_bfloat16 h = __float2bfloat16(v);
  return __builtin_bit_cast(unsigned short, h);
}

// ============== init + CSR prep + weight packing (one launch) ===============
// Also precomputes the step-0 LSTM state: qstar=h=c=0 -> gates=bih+bhh ->
// (h1,c1) is GRAPH-INDEPENDENT; broadcast into qbuf/hcbuf for all B graphs,
// removing the s2s_step<0> dispatch entirely.
__global__ void init_kernel(int* counts, int* gstart, int* gend,
                            float* rsum, float* lsum, float* sdbuf,
                            float* hcbuf, float* qbuf,
                            const float* __restrict__ bih, const float* __restrict__ bhh,
                            int* pad1, int* pad2, int npadints,
                            const float* __restrict__ W1, unsigned short* __restrict__ WT1,
                            const float* __restrict__ W2, unsigned short* __restrict__ WT2,
                            const float* __restrict__ W3, unsigned short* __restrict__ WT3,
                            int n, int b){
  int i = blockIdx.x*blockDim.x + threadIdx.x;
  if (i < n) counts[i] = 0;
  if (i < b){ gstart[i] = 0; gend[i] = 0; }
  if (i < 3*b*128) rsum[i] = 0.f;
  if (i < 3*b) lsum[i] = 0.f;
  if (i < 18*n) sdbuf[i] = 0.f;
  if (i < npadints){ pad1[i] = 0; pad2[i] = 0; }
  if (i < b*128){                   // step-0 LSTM, graph-independent
    int idx = i & 127, g = i >> 7;
    float ig = sigmoidf(bih[idx]     + bhh[idx]);
    float fg = sigmoidf(bih[128+idx] + bhh[128+idx]);  (void)fg;
    float gg = tanhf(bih[256+idx] + bhh[256+idx]);
    float og = sigmoidf(bih[384+idx] + bhh[384+idx]);
    float c1 = ig*gg;               // fg*c0 = 0
    float h1 = og*tanhf(c1);
    hcbuf[(size_t)g*128 + idx] = h1;
    hcbuf[(size_t)(b+g)*128 + idx] = c1;
    qbuf[(size_t)g*128 + idx] = h1;
  }
  if (i < 128*256){                 // W1 [128,256] -> WT1 [256][128]
    int k = i>>8, c = i&255;
    WT1[(size_t)c*128 + k] = bf16of(W1[i]);
  }
  if (i < 256*256){                 // W2 [256,256] -> WT2 [256][256]
    int k = i>>8, c = i&255;
    WT2[(size_t)c*256 + k] = bf16of(W2[i]);
  }
  if (i < 256*128){                 // W3 [256,128] -> WT3 [128][256]
    int k = i>>7, c = i&127;
    WT3[(size_t)c*256 + k] = bf16of(W3[i]);
  }
}

__global__ void build_kernel(const int* __restrict__ ei, const int* __restrict__ batch,
                             int* counts, int* gstart, int* gend, int E, int n){
  int i = blockIdx.x*blockDim.x + threadIdx.x;
  if (i < E) atomicAdd(&counts[ei[E+i]], 1);
  if (i < n){
    int b = batch[i];
    if (i == 0 || batch[i-1] != b) gstart[b] = i;
    if (i == n-1 || batch[i+1] != b) gend[b] = i+1;
  }
}

__global__ void scan_kernel(const int* __restrict__ counts, int* offs, int* cursor, int n){
  const int T = 1024;
  int tid = threadIdx.x;
  int chunk = (n + T - 1)/T;
  int base = tid*chunk;
  int local = 0;
  for (int i=0;i<chunk;i++){ int idx=base+i; if (idx<n) local += counts[idx]; }
  __shared__ int ss[T];
  ss[tid]=local; __syncthreads();
  for (int off=1; off<T; off<<=1){
    int v = (tid>=off)? ss[tid-off] : 0;
    __syncthreads();
    ss[tid]+=v;
    __syncthreads();
  }
  int run = ss[tid]-local;
  for (int i=0;i<chunk;i++){
    int idx=base+i;
    if (idx<n){ offs[idx]=run; cursor[idx]=run; run += counts[idx]; }
  }
  if (tid==T-1) offs[n]=run;
}

__global__ void fill_kernel(const int* __restrict__ ei, int* cursor, int* csr, int E){
  int i = blockIdx.x*blockDim.x + threadIdx.x;
  if (i<E){
    int dst = ei[E+i];
    int pos = atomicAdd(&cursor[dst],1);
    csr[pos] = ei[i];
  }
}

// ========================= plain-bf16 MFMA GEMM =============================
template<bool AF32, int H>
__global__ __launch_bounds__(256) void gemm_bf16(
    const void* __restrict__ Aptr, const short* __restrict__ BT,
    unsigned short* __restrict__ Cb16,
    const float* __restrict__ asrc, const float* __restrict__ adst,
    float* __restrict__ sv, float* __restrict__ dv,
    int M, int Ktot, int N){
  __shared__ short As[64][72];
  __shared__ short Bs[128][72];
  int tid = threadIdx.x;
  int wave = tid>>6, lane = tid&63;
  int quad = lane>>4, l16 = lane&15;
  int bm = blockIdx.y*64, bn = blockIdx.x*128;
  f32x4 acc[8];
  #pragma unroll
  for (int i=0;i<8;i++) acc[i] = (f32x4){0.f,0.f,0.f,0.f};
  int rr = tid>>3;          // 0..31
  int seg = (tid&7)*8;      // shorts (= bf16 elements = k index)
  int4 ra[2], rb[4];
  auto loadAB = [&](int k0){
    if (AF32){
      const float* A = (const float*)Aptr;
      #pragma unroll
      for (int p=0;p<2;p++){
        int row = bm + p*32 + rr;
        float4 v0 = make_float4(0.f,0.f,0.f,0.f), v1 = v0;
        if (row < M){
          const float* ap = A + (size_t)row*Ktot + k0 + seg;
          v0 = *(const float4*)(ap);
          v1 = *(const float4*)(ap+4);
        }
        unsigned u0 = (unsigned)bf16of(v0.x) | ((unsigned)bf16of(v0.y)<<16);
        unsigned u1 = (unsigned)bf16of(v0.z) | ((unsigned)bf16of(v0.w)<<16);
        unsigned u2 = (unsigned)bf16of(v1.x) | ((unsigned)bf16of(v1.y)<<16);
        unsigned u3 = (unsigned)bf16of(v1.z) | ((unsigned)bf16of(v1.w)<<16);
        ra[p] = make_int4((int)u0,(int)u1,(int)u2,(int)u3);
      }
    } else {
      const short* A = (const short*)Aptr;
      #pragma unroll
      for (int p=0;p<2;p++)
        ra[p] = *(const int4*)(A + (size_t)(bm + p*32 + rr)*Ktot + k0 + seg);
    }
    #pragma unroll
    for (int p=0;p<4;p++)
      rb[p] = *(const int4*)(BT + (size_t)(bn + p*32 + rr)*Ktot + k0 + seg);
  };
  loadAB(0);
  for (int k0=0; k0<Ktot; k0+=64){
    __syncthreads();
    #pragma unroll
    for (int p=0;p<2;p++) *(int4*)&As[p*32+rr][seg] = ra[p];
    #pragma unroll
    for (int p=0;p<4;p++) *(int4*)&Bs[p*32+rr][seg] = rb[p];
    __syncthreads();
    if (k0+64 < Ktot) loadAB(k0+64);   // prefetch; regs free (already stored)
    #pragma unroll
    for (int kk=0;kk<2;kk++){
      bf16x8 af = *(bf16x8*)&As[wave*16 + l16][kk*32 + quad*8];
      #pragma unroll
      for (int nf=0;nf<8;nf++){
        bf16x8 bfv = *(bf16x8*)&Bs[nf*16 + l16][kk*32 + quad*8];
        acc[nf] = __builtin_amdgcn_mfma_f32_16x16x32_bf16(af, bfv, acc[nf], 0,0,0);
      }
    }
  }
  // ---- fused sd: partial <h,a> dots from exact fp32 acc ----
  float av[8], bv[8];
  #pragma unroll
  for (int nf=0;nf<8;nf++){
    int c = bn + nf*16 + l16;
    av[nf] = asrc[c];
    bv[nf] = adst[c];
  }
  #pragma unroll
  for (int r=0;r<4;r++){
    int row = bm + wave*16 + quad*4 + r;
    float psA=0.f, pdA=0.f, psB=0.f, pdB=0.f;
    #pragma unroll
    for (int nf=0;nf<4;nf++){ psA += acc[nf][r]*av[nf]; pdA += acc[nf][r]*bv[nf]; }
    #pragma unroll
    for (int nf=4;nf<8;nf++){ psB += acc[nf][r]*av[nf]; pdB += acc[nf][r]*bv[nf]; }
    #pragma unroll
    for (int off=1; off<16; off<<=1){
      psA += __shfl_xor(psA,off); pdA += __shfl_xor(pdA,off);
      psB += __shfl_xor(psB,off); pdB += __shfl_xor(pdB,off);
    }
    if (l16==0 && row < M){
      if (H == 4){
        int h0 = bn>>6;
        atomicAdd(&sv[row*4 + h0],     psA);
        atomicAdd(&dv[row*4 + h0],     pdA);
        atomicAdd(&sv[row*4 + h0 + 1], psB);
        atomicAdd(&dv[row*4 + h0 + 1], pdB);
      } else {
        atomicAdd(&sv[row], psA + psB);
        atomicAdd(&dv[row], pdA + pdB);
      }
    }
  }
  // ---- coalesced bf16 epilogue: quad stages+writes its own row ----
  __syncthreads();                       // all frag reads done; reuse As
  unsigned short* stgS = (unsigned short*)(&As[0][0]) + wave*1056; // 4 x 264
  #pragma unroll
  for (int r=0;r<4;r++){
    #pragma unroll
    for (int nf=0;nf<8;nf++)
      stgS[quad*264 + nf*16 + l16] = bf16of(acc[nf][r]);   // row quad*4+r
    int row = bm + wave*16 + quad*4 + r;
    if (row < M){
      int4 v = *(int4*)(stgS + quad*264 + l16*8);          // 8 shorts/lane
      *(int4*)(Cb16 + (size_t)row*N + bn + l16*8) = v;     // 16 lanes = 256B
    }
  }
}

// ================= GAT aggregation: 64-ch slices, 16 lanes/node =============
template<int H, int C, bool SPLIT>
__global__ __launch_bounds__(256) void agg_kernel(
    const unsigned short* __restrict__ hb, const float* __restrict__ s,
    const float* __restrict__ d, const int* __restrict__ offs,
    const int* __restrict__ csr, const float* __restrict__ bias,
    float* __restrict__ yf, unsigned short* __restrict__ ys, int n_nodes){
  constexpr int HC = H*C;
  constexpr int SLICES = HC/64;        // 4 (HC=256) or 2 (HC=128)
  int bx = blockIdx.x;
  int sl = bx % SLICES;
  int ng = bx / SLICES;
  int tid = threadIdx.x;
  int grp = tid >> 4;                  // node within the 16-node group
  int l4  = tid & 15;                  // lane within node
  int n = ng*16 + grp;
  if (n >= n_nodes) return;
  int c0 = sl*64 + l4*4;               // 4 channels per lane
  int head = c0 / C;                   // uniform per group (C=64: head=sl)
  float ddst = d[n*H + head];
  int start = offs[n];
  int cnt = offs[n+1] - start;
  int cnt1 = cnt + 1;                  // + self loop
  float a0=0.f, a1=0.f, a2=0.f, a3=0.f, lp=0.f;
  for (int base=0; base<cnt1; base+=16){
    int nchunk = min(16, cnt1-base);
    int srcv = 0; float wv = 0.f;
    if (l4 < nchunk){
      int i = base + l4;
      srcv = (i==cnt) ? n : csr[start+i];
      float e = s[srcv*H + head] + ddst;
      e = e>=0.f ? e : NEG_SLOPE*e;
      wv = expf(e);
      lp += wv;
    }
    for (int j=0;j<nchunk;j++){
      int sj = __shfl(srcv, j, 16);
      float wj = __shfl(wv, j, 16);
      int2 hv = *reinterpret_cast<const int2*>(hb + (size_t)sj*HC + c0);
      a0 += wj*bf2f((unsigned)hv.x & 0xFFFFu);
      a1 += wj*bf2f((unsigned)hv.x >> 16);
      a2 += wj*bf2f((unsigned)hv.y & 0xFFFFu);
      a3 += wj*bf2f((unsigned)hv.y >> 16);
    }
  }
  #pragma unroll
  for (int off=1; off<16; off<<=1) lp += __shfl_xor(lp, off, 16);
  float inv = 1.f/(lp + 1e-16f);
  float o[4] = {a0*inv, a1*inv, a2*inv, a3*inv};
  #pragma unroll
  for (int v=0;v<4;v++){
    float t = o[v] + bias[c0+v];
    o[v] = t>0.f ? t : expm1f(t);
  }
  if (SPLIT){
    unsigned u0 = (unsigned)bf16of(o[0]) | ((unsigned)bf16of(o[1])<<16);
    unsigned u1 = (unsigned)bf16of(o[2]) | ((unsigned)bf16of(o[3])<<16);
    *reinterpret_cast<uint2*>(ys + (size_t)n*HC + c0) = make_uint2(u0,u1);
  } else {
    float4 fv = make_float4(o[0], o[1], o[2], o[3]);
    *reinterpret_cast<float4*>(yf + (size_t)n*HC + c0) = fv;
  }
}

// ======================= Set2Set, grid-parallel =============================
__global__ __launch_bounds__(256) void read_kernel(
    const float* __restrict__ x, const float* __restrict__ q,
    const int* __restrict__ batch,
    float* __restrict__ rsum, float* __restrict__ lsum, int N){
  int tid = threadIdx.x;
  int wave = tid>>6, lane = tid&63;
  int c0 = blockIdx.x*32;
  if (c0 >= N) return;
  __shared__ float ws[32];
  __shared__ int gb[32];
  if (tid < 32 && c0+tid < N) gb[tid] = batch[c0+tid];
  __syncthreads();
  #pragma unroll
  for (int j=0;j<8;j++){
    int k = wave*8 + j;
    int i = c0 + k;
    if (i < N){
      int g = gb[k];
      float2 xv = *reinterpret_cast<const float2*>(x + (size_t)i*128 + lane*2);
      float2 qv = *reinterpret_cast<const float2*>(q + (size_t)g*128 + lane*2);
      float p = xv.x*qv.x + xv.y*qv.y;
      #pragma unroll
      for (int off=32; off; off>>=1) p += __shfl_down(p, off);
      if (lane==0) ws[k] = expf(p);
    }
  }
  __syncthreads();
  if (tid < 128){
    int col = tid;
    int endi = min(c0+32, N);
    int curg = gb[0];
    float acc = 0.f, lacc = 0.f;
    for (int i=c0; i<endi; ++i){
      int g = gb[i-c0];
      if (g != curg){
        atomicAdd(&rsum[curg*128+col], acc);
        if (col==0) atomicAdd(&lsum[curg], lacc);
        acc = 0.f; lacc = 0.f; curg = g;
      }
      float w = ws[i-c0];
      acc += w * x[(size_t)i*128+col];
      lacc += w;
    }
    atomicAdd(&rsum[curg*128+col], acc);
    if (col==0) atomicAdd(&lsum[curg], lacc);
  }
}

template<int STEP>
__global__ __launch_bounds__(256) void s2s_step_kernel(
    const float* __restrict__ rsum, const float* __restrict__ lsum,
    float* __restrict__ hc, float* __restrict__ qbuf,
    const float* __restrict__ Wih, const float* __restrict__ Whh,
    const float* __restrict__ bih, const float* __restrict__ bhh,
    const float* __restrict__ gfeat,
    const float* __restrict__ gW1, const float* __restrict__ gb1,
    const float* __restrict__ gW2, const float* __restrict__ gb2,
    const float* __restrict__ mW1, const float* __restrict__ mb1,
    const float* __restrict__ mW2, const float* __restrict__ mb2,
    float* __restrict__ out, int B){
  int b = blockIdx.x, tid = threadIdx.x;
  __shared__ float qs[256];

  if (tid < 128){
    const float* rs = rsum + (size_t)(STEP-1)*B*128 + (size_t)b*128;
    float ls = lsum[(STEP-1)*B + b];
    qs[tid]     = qbuf[b*128+tid];
    qs[128+tid] = rs[tid] / (ls + 1e-16f);
  }
  __syncthreads();

  if (STEP < 3){
    __shared__ float hs[128], gsh[512];
    if (tid<128) hs[tid] = hc[(size_t)b*128+tid];
    __syncthreads();
    #pragma unroll
    for (int p=0;p<2;p++){
      int j = tid + p*256;
      float a = bih[j] + bhh[j];
      const float* wi = Wih + (size_t)j*256;
      for (int k=0;k<256;k+=4)
        a += qs[k]*wi[k] + qs[k+1]*wi[k+1] + qs[k+2]*wi[k+2] + qs[k+3]*wi[k+3];
      const float* wh = Whh + (size_t)j*128;
      for (int k=0;k<128;k+=4)
        a += hs[k]*wh[k] + hs[k+1]*wh[k+1] + hs[k+2]*wh[k+2] + hs[k+3]*wh[k+3];
      gsh[j] = a;
    }
    __syncthreads();
    if (tid < 128){
      float cprev = hc[(size_t)(B+b)*128+tid];
      float ig = sigmoidf(gsh[tid]);
      float fg = sigmoidf(gsh[128+tid]);
      float gg = tanhf(gsh[256+tid]);
      float og = sigmoidf(gsh[384+tid]);
      float c2 = fg*cprev + ig*gg;
      float h2 = og*tanhf(c2);
      hc[(size_t)b*128+tid] = h2;
      hc[(size_t)(B+b)*128+tid] = c2;
      qbuf[b*128+tid] = h2;
    }
  } else {
    __shared__ float z[288], gf1[64], hid[128];
    z[tid] = qs[tid];
    if (tid < 64){
      float a = gb1[tid];
      for (int k=0;k<9;k++) a += gfeat[b*9+k]*gW1[k*64+tid];
      gf1[tid] = a>0.f ? a : 0.f;
    }
    __syncthreads();
    if (tid < 32){
      float a = gb2[tid];
      for (int k=0;k<64;k++) a += gf1[k]*gW2[k*32+tid];
      z[256+tid] = a;
    }
    __syncthreads();
    if (tid < 128){
      float a = mb1[tid];
      for (int k=0;k<288;k++) a += z[k]*mW1[(size_t)k*128+tid];
      hid[tid] = a>0.f ? a : 0.f;
    }
    __syncthreads();
    if (tid < 4){
      float a = mb2[tid];
      for (int k=0;k<128;k++) a += hid[k]*mW2[k*4+tid];
      out[b*4+tid] = a;
    }
  }
}

// ================================ launch ====================================
extern "C" void kernel_launch(void* const* d_in, const int* in_sizes, int n_in,
                              void* d_out, int out_size, void* d_ws, size_t ws_size,
                              hipStream_t stream) {
  const float* x     = (const float*)d_in[0];
  const int*   ei    = (const int*)d_in[1];
  const int*   batch = (const int*)d_in[2];
  const float* gfeat = (const float*)d_in[3];
  const float* W1    = (const float*)d_in[4];
  const float* as1   = (const float*)d_in[5];
  const float* ad1   = (const float*)d_in[6];
  const float* b1    = (const float*)d_in[7];
  const float* W2    = (const float*)d_in[8];
  const float* as2   = (const float*)d_in[9];
  const float* ad2   = (const float*)d_in[10];
  const float* b2    = (const float*)d_in[11];
  const float* W3    = (const float*)d_in[12];
  const float* as3   = (const float*)d_in[13];
  const float* ad3   = (const float*)d_in[14];
  const float* b3    = (const float*)d_in[15];
  const float* Wih   = (const float*)d_in[16];
  const float* Whh   = (const float*)d_in[17];
  const float* bih   = (const float*)d_in[18];
  const float* bhh   = (const float*)d_in[19];
  const float* gW1   = (const float*)d_in[20];
  const float* gb1   = (const float*)d_in[21];
  const float* gW2   = (const float*)d_in[22];
  const float* gb2   = (const float*)d_in[23];
  const float* mW1   = (const float*)d_in[24];
  const float* mb1   = (const float*)d_in[25];
  const float* mW2   = (const float*)d_in[26];
  const float* mb2   = (const float*)d_in[27];

  const int N = in_sizes[0]/128;   // 20000
  const int E = in_sizes[1]/2;     // 320000
  const int B = in_sizes[3]/9;     // 64
  const int Mpad = ((N + 127)/128)*128;   // 20096

  char* ws = (char*)d_ws;
  size_t off = 0;
  auto alloc = [&](size_t bytes)->char*{
    char* p = ws + off;
    off += (bytes + 255) & ~(size_t)255;
    return p;
  };
  unsigned short* hb16 = (unsigned short*)alloc((size_t)N*256*2);   // bf16 h
  unsigned short* y1   = (unsigned short*)alloc((size_t)Mpad*256*2);// bf16 y1
  unsigned short* y2   = (unsigned short*)alloc((size_t)Mpad*256*2);// bf16 y2
  float*    ybuf    = (float*)alloc((size_t)N*128*4);
  unsigned short* WT1 = (unsigned short*)alloc((size_t)256*128*2);
  unsigned short* WT2 = (unsigned short*)alloc((size_t)256*256*2);
  unsigned short* WT3 = (unsigned short*)alloc((size_t)128*256*2);
  float* sdbuf  = (float*)alloc((size_t)18*N*4);   // s1 d1 s2 d2 s3 d3
  int*   counts = (int*)alloc((size_t)N*4);
  int*   offs   = (int*)alloc((size_t)(N+1)*4);
  int*   cursor = (int*)alloc((size_t)N*4);
  int*   csr    = (int*)alloc((size_t)E*4);
  int*   gstart = (int*)alloc((size_t)B*4);
  int*   gend   = (int*)alloc((size_t)B*4);
  float* hcbuf  = (float*)alloc((size_t)2*B*128*4);
  float* qbuf   = (float*)alloc((size_t)B*128*4);
  float* rsum   = (float*)alloc((size_t)3*B*128*4);
  float* lsum   = (float*)alloc((size_t)3*B*4);

  float* s1 = sdbuf;            float* d1 = sdbuf + (size_t)4*N;
  float* s2 = sdbuf + (size_t)8*N;  float* d2 = sdbuf + (size_t)12*N;
  float* s3 = sdbuf + (size_t)16*N; float* d3 = sdbuf + (size_t)17*N;

  int npadints = (Mpad - N)*128;   // pad rows x 256 shorts / 2 per int
  int nInit = 18*N;
  if (npadints > nInit) nInit = npadints;
  if (256*256 > nInit) nInit = 256*256;
  init_kernel<<<(nInit+255)/256, 256, 0, stream>>>(counts, gstart, gend,
      rsum, lsum, sdbuf, hcbuf, qbuf, bih, bhh,
      (int*)(y1 + (size_t)N*256), (int*)(y2 + (size_t)N*256),
      npadints, W1, WT1, W2, WT2, W3, WT3, N, B);
  int gridEN = (max(E,N)+255)/256;
  build_kernel<<<gridEN, 256, 0, stream>>>(ei, batch, counts, gstart, gend, E, N);
  scan_kernel<<<1, 1024, 0, stream>>>(counts, offs, cursor, N);
  fill_kernel<<<(E+255)/256, 256, 0, stream>>>(ei, cursor, csr, E);

  int gm = Mpad/64;
  int ng16 = (N+15)/16;
  // ---- layer 1: x (fp32->bf16 inline, K=128) -> h bf16 + s1,d1 -> y1
  gemm_bf16<true,4><<<dim3(2,gm), 256, 0, stream>>>((const void*)x, (const short*)WT1,
      hb16, as1, ad1, s1, d1, N, 128, 256);
  agg_kernel<4,64,true><<<ng16*4, 256, 0, stream>>>(hb16, s1, d1, offs, csr, b1, nullptr, y1, N);
  // ---- layer 2: y1 (bf16, K=256) -> h bf16 + s2,d2 -> y2
  gemm_bf16<false,4><<<dim3(2,gm), 256, 0, stream>>>((const void*)y1, (const short*)WT2,
      hb16, as2, ad2, s2, d2, N, 256, 256);
  agg_kernel<4,64,true><<<ng16*4, 256, 0, stream>>>(hb16, s2, d2, offs, csr, b2, nullptr, y2, N);
  // ---- layer 3: y2 (bf16, K=256) -> h bf16 [N,128] + s3,d3 -> ybuf (fp32)
  gemm_bf16<false,1><<<dim3(1,gm), 256, 0, stream>>>((const void*)y2, (const short*)WT3,
      hb16, as3, ad3, s3, d3, N, 256, 128);
  agg_kernel<1,128,false><<<ng16*2, 256, 0, stream>>>(hb16, s3, d3, offs, csr, b3, ybuf, nullptr, N);

  // ---- set2set (grid-parallel readout; step-0 LSTM precomputed in init) ----
  int gr = (N+31)/32;
  read_kernel<<<gr, 256, 0, stream>>>(ybuf, qbuf, batch, rsum + 0*(size_t)B*128, lsum + 0*B, N);
  s2s_step_kernel<1><<<B, 256, 0, stream>>>(rsum, lsum, hcbuf, qbuf,
      Wih, Whh, bih, bhh, gfeat, gW1, gb1, gW2, gb2, mW1, mb1, mW2, mb2, (float*)d_out, B);
  read_kernel<<<gr, 256, 0, stream>>>(ybuf, qbuf, batch, rsum + 1*(size_t)B*128, lsum + 1*B, N);
  s2s_step_kernel<2><<<B, 256, 0, stream>>>(rsum, lsum, hcbuf, qbuf,
      Wih, Whh, bih, bhh, gfeat, gW1, gb1, gW2, gb2, mW1, mb1, mW2, mb2, (float*)d_out, B);
  read_kernel<<<gr, 256, 0, stream>>>(ybuf, qbuf, batch, rsum + 2*(size_t)B*128, lsum + 2*B, N);
  s2s_step_kernel<3><<<B, 256, 0, stream>>>(rsum, lsum, hcbuf, qbuf,
      Wih, Whh, bih, bhh, gfeat, gW1, gb1, gW2, gb2, mW1, mb1, mW2, mb2, (float*)d_out, B);
}